// Round 1
// baseline (426.863 us; speedup 1.0000x reference)
//
#include <hip/hip_runtime.h>
#include <math.h>

// Problem constants
#define Bb 8
#define Kk 32
#define Hh 480
#define Ww 480
#define Nn 576
#define Dd 1024
#define CLSD 64
#define OUTD 256
#define INDIM 1093
#define INPAD 1152
#define BK 256           // B*K
#define PIX4 57600       // 480*480/4 int4 per (b,k)

// ws layout (in floats)
#define DS_OFF   0                     // [BK][576] downsampled masks  (later reused as h-row scratch by kernel C)
#define META_OFF 147456                // [BK][8]: geom[5], inv_msum, count, pad
#define X_OFF    149504                // [BK][INPAD] x rows
// total = 149504 + 256*1152 = 444416 floats = 1.78 MB

// ---------------- Kernel A: full-res mask scan ----------------
// One block per (b,k). Reads 900 KB of int32 mask, produces:
//  - ds[576]: 24x24 nearest-neighbor mask (float 0/1)
//  - geom[5] + inv_msum + count into meta
__global__ __launch_bounds__(1024) void kA(const int* __restrict__ masks,
                                           float* __restrict__ ws) {
  const int bk = blockIdx.x;
  const int t  = threadIdx.x;
  const int4* mp = (const int4*)(masks + (size_t)bk * (Hh * Ww));

  __shared__ float ds[576];
  __shared__ int s_area, s_sumx, s_sumy, s_cnt;
  __shared__ int s_minx, s_maxx, s_miny, s_maxy;
  if (t == 0) {
    s_area = 0; s_sumx = 0; s_sumy = 0; s_cnt = 0;
    s_minx = Ww; s_maxx = -1; s_miny = Hh; s_maxy = -1;
  }
  __syncthreads();

  int area = 0, sumx = 0, sumy = 0, cntds = 0;
  int minx = Ww, maxx = -1, miny = Hh, maxy = -1;

  for (int q = t; q < PIX4; q += 1024) {
    int4 v = mp[q];
    int h   = q / 120;          // 120 int4 per row
    int rem = q - h * 120;
    int w0  = rem * 4;
    int m0 = v.x > 0, m1 = v.y > 0, m2 = v.z > 0, m3 = v.w > 0;
    int c = m0 + m1 + m2 + m3;
    area += c;
    sumy += h * c;
    sumx += w0 * c + m1 + 2 * m2 + 3 * m3;
    if (c) {
      miny = min(miny, h);
      maxy = max(maxy, h);
      int lo = m0 ? w0 : (m1 ? w0 + 1 : (m2 ? w0 + 2 : w0 + 3));
      int hi = m3 ? w0 + 3 : (m2 ? w0 + 2 : (m1 ? w0 + 1 : w0));
      minx = min(minx, lo);
      maxx = max(maxx, hi);
    }
    // downsample: pixel (h, w0) with h%20==0 and w0%20==0 (w0%20==0 <=> rem%5==0)
    int a20 = h / 20;
    int c5  = rem / 5;
    if (h == a20 * 20 && rem == c5 * 5) {
      ds[a20 * 24 + c5] = (float)m0;
      cntds += m0;
    }
  }

  // wave (64-lane) reduction
  for (int off = 32; off; off >>= 1) {
    area  += __shfl_down(area, off);
    sumx  += __shfl_down(sumx, off);
    sumy  += __shfl_down(sumy, off);
    cntds += __shfl_down(cntds, off);
    minx = min(minx, __shfl_down(minx, off));
    maxx = max(maxx, __shfl_down(maxx, off));
    miny = min(miny, __shfl_down(miny, off));
    maxy = max(maxy, __shfl_down(maxy, off));
  }
  if ((t & 63) == 0) {
    atomicAdd(&s_area, area);
    atomicAdd(&s_sumx, sumx);
    atomicAdd(&s_sumy, sumy);
    atomicAdd(&s_cnt, cntds);
    atomicMin(&s_minx, minx);
    atomicMax(&s_maxx, maxx);
    atomicMin(&s_miny, miny);
    atomicMax(&s_maxy, maxy);
  }
  __syncthreads();

  float* ws_ds = ws + DS_OFF + (size_t)bk * 576;
  if (t < 576) ws_ds[t] = ds[t];

  if (t == 0) {
    float* meta = ws + META_OFF + (size_t)bk * 8;
    float areaf = (float)s_area;
    float safe  = fmaxf(areaf, 1.0f);
    float cx = ((float)s_sumx / safe) * (1.0f / Ww);
    float cy = ((float)s_sumy / safe) * (1.0f / Hh);
    float an = areaf * (1.0f / (Hh * Ww));
    float bw = (float)(s_maxx - s_minx + 1) * (1.0f / Ww);
    float bh = (float)(s_maxy - s_miny + 1) * (1.0f / Hh);
    if (s_area < 1) { cx = 0.f; cy = 0.f; an = 0.f; bw = 0.f; bh = 0.f; }
    meta[0] = cx; meta[1] = cy; meta[2] = an; meta[3] = bw; meta[4] = bh;
    meta[5] = 1.0f / fmaxf((float)s_cnt, 1e-6f);
    meta[6] = (float)s_cnt;
  }
}

// ---------------- Kernel B: masked pooling + x row build ----------------
// One block per (b,k); b = blockIdx%8 so all k-blocks of one b share an XCD L2.
__global__ __launch_bounds__(256) void kB(const float* __restrict__ fm,
                                          const int* __restrict__ cids,
                                          const float* __restrict__ emb,
                                          float* __restrict__ ws) {
  const int b  = blockIdx.x & 7;
  const int k  = blockIdx.x >> 3;
  const int bk = b * Kk + k;
  const int t  = threadIdx.x;

  __shared__ float msh[576];
  __shared__ int act[576];
  __shared__ int nact;
  if (t == 0) nact = 0;
  __syncthreads();

  const float* ws_ds = ws + DS_OFF + (size_t)bk * 576;
  for (int i = t; i < 576; i += 256) {
    float mv = ws_ds[i];
    msh[i] = mv;
    if (mv != 0.0f) {
      int p = atomicAdd(&nact, 1);
      act[p] = i;
    }
  }
  __syncthreads();
  const int na = nact;

  float ax = 0.f, ay = 0.f, az = 0.f, aw = 0.f;
  const float4* fmp = (const float4*)fm + (size_t)b * Nn * (Dd / 4);
  int j = 0;
  for (; j + 4 <= na; j += 4) {
    int4 nn = *(const int4*)(act + j);
    float4 f0 = fmp[nn.x * (Dd / 4) + t];
    float4 f1 = fmp[nn.y * (Dd / 4) + t];
    float4 f2 = fmp[nn.z * (Dd / 4) + t];
    float4 f3 = fmp[nn.w * (Dd / 4) + t];
    ax += f0.x + f1.x + f2.x + f3.x;
    ay += f0.y + f1.y + f2.y + f3.y;
    az += f0.z + f1.z + f2.z + f3.z;
    aw += f0.w + f1.w + f2.w + f3.w;
  }
  for (; j < na; j++) {
    float4 f = fmp[act[j] * (Dd / 4) + t];
    ax += f.x; ay += f.y; az += f.z; aw += f.w;
  }

  const float* meta = ws + META_OFF + (size_t)bk * 8;
  float inv = meta[5];
  float* xrow = ws + X_OFF + (size_t)bk * INPAD;
  float4 p4;
  p4.x = ax * inv; p4.y = ay * inv; p4.z = az * inv; p4.w = aw * inv;
  ((float4*)xrow)[t] = p4;

  if (t < CLSD) {
    int cid = cids[bk];
    xrow[Dd + t] = emb[cid * CLSD + t];
  } else if (t < CLSD + 5) {
    xrow[Dd + CLSD + (t - CLSD)] = meta[t - CLSD];
  } else if (t < CLSD + 5 + (INPAD - INDIM)) {
    xrow[INDIM + (t - CLSD - 5)] = 0.0f;
  }
}

// ---------------- Kernel C: MLP (GEMV + GeLU + LN + GEMV), 2 rows/block ----------------
__global__ __launch_bounds__(256) void kC(float* __restrict__ ws,
                                          const float* __restrict__ W1,
                                          const float* __restrict__ b1,
                                          const float* __restrict__ lg,
                                          const float* __restrict__ lb,
                                          const float* __restrict__ W2,
                                          const float* __restrict__ b2,
                                          float* __restrict__ out) {
  const int o  = threadIdx.x;
  const int r0 = blockIdx.x * 2;
  const float* x0 = ws + X_OFF + (size_t)r0 * INPAD;
  const float* x1 = x0 + INPAD;

  float a0 = b1[o], a1 = b1[o];
  for (int i = 0; i < 1092; i += 4) {
    float4 va = *(const float4*)(x0 + i);
    float4 vb = *(const float4*)(x1 + i);
    const float* fa = (const float*)&va;
    const float* fb = (const float*)&vb;
#pragma unroll
    for (int jj = 0; jj < 4; jj++) {
      float w = W1[(i + jj) * OUTD + o];
      a0 = fmaf(fa[jj], w, a0);
      a1 = fmaf(fb[jj], w, a1);
    }
  }
  {  // tail i = 1092
    float w = W1[1092 * OUTD + o];
    a0 = fmaf(x0[1092], w, a0);
    a1 = fmaf(x1[1092], w, a1);
  }

  // exact GeLU
  a0 = 0.5f * a0 * (1.0f + erff(a0 * 0.7071067811865475f));
  a1 = 0.5f * a1 * (1.0f + erff(a1 * 0.7071067811865475f));

  // LayerNorm stats across 256 threads (4 waves)
  __shared__ float sm0[4], sv0[4], sm1[4], sv1[4];
  float s0 = a0, q0 = a0 * a0, s1 = a1, q1 = a1 * a1;
  for (int off = 32; off; off >>= 1) {
    s0 += __shfl_down(s0, off);
    q0 += __shfl_down(q0, off);
    s1 += __shfl_down(s1, off);
    q1 += __shfl_down(q1, off);
  }
  const int wid = o >> 6, lane = o & 63;
  if (lane == 0) { sm0[wid] = s0; sv0[wid] = q0; sm1[wid] = s1; sv1[wid] = q1; }
  __syncthreads();
  float mu0 = (sm0[0] + sm0[1] + sm0[2] + sm0[3]) * (1.0f / OUTD);
  float mu1 = (sm1[0] + sm1[1] + sm1[2] + sm1[3]) * (1.0f / OUTD);
  float va0 = (sv0[0] + sv0[1] + sv0[2] + sv0[3]) * (1.0f / OUTD) - mu0 * mu0;
  float va1 = (sv1[0] + sv1[1] + sv1[2] + sv1[3]) * (1.0f / OUTD) - mu1 * mu1;
  float is0 = 1.0f / sqrtf(va0 + 1e-5f);
  float is1 = 1.0f / sqrtf(va1 + 1e-5f);
  float g = lg[o], bb = lb[o];
  float h0 = (a0 - mu0) * is0 * g + bb;
  float h1 = (a1 - mu1) * is1 * g + bb;

  // stage hn rows in ws (reuse DS region) for uniform-address re-reads
  float* wsh = ws + DS_OFF;
  wsh[(size_t)r0 * OUTD + o] = h0;
  wsh[(size_t)(r0 + 1) * OUTD + o] = h1;
  __threadfence_block();
  __syncthreads();

  const float* h0p = wsh + (size_t)r0 * OUTD;
  const float* h1p = h0p + OUTD;
  float c0 = b2[o], c1 = b2[o];
  for (int i = 0; i < OUTD; i += 4) {
    float4 ha = *(const float4*)(h0p + i);
    float4 hb = *(const float4*)(h1p + i);
    const float* fa = (const float*)&ha;
    const float* fb = (const float*)&hb;
#pragma unroll
    for (int jj = 0; jj < 4; jj++) {
      float w = W2[(i + jj) * OUTD + o];
      c0 = fmaf(fa[jj], w, c0);
      c1 = fmaf(fb[jj], w, c1);
    }
  }
  out[(size_t)r0 * OUTD + o] = c0;
  out[(size_t)(r0 + 1) * OUTD + o] = c1;
}

extern "C" void kernel_launch(void* const* d_in, const int* in_sizes, int n_in,
                              void* d_out, int out_size, void* d_ws, size_t ws_size,
                              hipStream_t stream) {
  const float* fm    = (const float*)d_in[0];
  const int*   masks = (const int*)d_in[1];
  const int*   cids  = (const int*)d_in[2];
  const float* emb   = (const float*)d_in[3];
  const float* W1    = (const float*)d_in[4];
  const float* b1    = (const float*)d_in[5];
  const float* lg    = (const float*)d_in[6];
  const float* lb    = (const float*)d_in[7];
  const float* W2    = (const float*)d_in[8];
  const float* b2    = (const float*)d_in[9];
  float* out = (float*)d_out;
  float* ws  = (float*)d_ws;

  hipLaunchKernelGGL(kA, dim3(BK), dim3(1024), 0, stream, masks, ws);
  hipLaunchKernelGGL(kB, dim3(BK), dim3(256), 0, stream, fm, cids, emb, ws);
  hipLaunchKernelGGL(kC, dim3(BK / 2), dim3(256), 0, stream, ws, W1, b1, lg, lb, W2, b2, out);
}

// Round 2
// 415.372 us; speedup vs baseline: 1.0277x; 1.0277x over previous
//
#include <hip/hip_runtime.h>
#include <math.h>

// Problem constants
#define Bb 8
#define Kk 32
#define Hh 480
#define Ww 480
#define Nn 576
#define Dd 1024
#define CLSD 64
#define OUTD 256
#define INDIM 1093
#define BK 256           // B*K
#define PIX4 57600       // 480*480/4 int4 per (b,k)

// ws layout (floats)
#define DS_OFF   0                     // [BK][576] downsampled masks
#define META_OFF 147456                // [BK][8]: geom[5], inv_msum, cnt, pad

// ---------------- Kernel A: full-res mask scan ----------------
// One block per (b,k). Reads 900 KB of int32 mask (HBM floor for the whole
// problem: 236 MB total), produces ds[576] (24x24 nearest mask) + meta.
__global__ __launch_bounds__(1024) void kA(const int* __restrict__ masks,
                                           float* __restrict__ ws) {
  const int bk = blockIdx.x;
  const int t  = threadIdx.x;
  const int4* mp = (const int4*)(masks + (size_t)bk * (Hh * Ww));

  __shared__ float ds[576];
  __shared__ int s_area, s_sumx, s_sumy, s_cnt;
  __shared__ int s_minx, s_maxx, s_miny, s_maxy;
  if (t == 0) {
    s_area = 0; s_sumx = 0; s_sumy = 0; s_cnt = 0;
    s_minx = Ww; s_maxx = -1; s_miny = Hh; s_maxy = -1;
  }
  __syncthreads();

  int area = 0, sumx = 0, sumy = 0, cntds = 0;
  int minx = Ww, maxx = -1, miny = Hh, maxy = -1;

  auto body = [&](int q, int4 v) {
    int h   = q / 120;          // 120 int4 per row (compiler magic-muls)
    int rem = q - h * 120;
    int w0  = rem * 4;
    int m0 = v.x > 0, m1 = v.y > 0, m2 = v.z > 0, m3 = v.w > 0;
    int c = m0 + m1 + m2 + m3;
    area += c;
    sumy += h * c;
    sumx += w0 * c + m1 + 2 * m2 + 3 * m3;
    if (c) {
      miny = min(miny, h);
      maxy = max(maxy, h);
      int lo = m0 ? w0 : (m1 ? w0 + 1 : (m2 ? w0 + 2 : w0 + 3));
      int hi = m3 ? w0 + 3 : (m2 ? w0 + 2 : (m1 ? w0 + 1 : w0));
      minx = min(minx, lo);
      maxx = max(maxx, hi);
    }
    // downsample sample points: h%20==0 && w0%20==0 (w0%20==0 <=> rem%5==0)
    int a20 = h / 20;
    int c5  = rem / 5;
    if (h == a20 * 20 && rem == c5 * 5) {
      ds[a20 * 24 + c5] = (float)m0;
      cntds += m0;
    }
  };

  // uniform main loop (56 iters covers q < 57344) + 256-element tail;
  // unroll 4 => 4 outstanding 1KB/wave dwordx4 loads for latency hiding
#pragma unroll 4
  for (int i = 0; i < 56; i++) {
    int q = t + (i << 10);
    body(q, mp[q]);
  }
  if (t < 256) {
    int q = 57344 + t;
    body(q, mp[q]);
  }

  // wave (64-lane) reduction
  for (int off = 32; off; off >>= 1) {
    area  += __shfl_down(area, off);
    sumx  += __shfl_down(sumx, off);
    sumy  += __shfl_down(sumy, off);
    cntds += __shfl_down(cntds, off);
    minx = min(minx, __shfl_down(minx, off));
    maxx = max(maxx, __shfl_down(maxx, off));
    miny = min(miny, __shfl_down(miny, off));
    maxy = max(maxy, __shfl_down(maxy, off));
  }
  if ((t & 63) == 0) {
    atomicAdd(&s_area, area);
    atomicAdd(&s_sumx, sumx);
    atomicAdd(&s_sumy, sumy);
    atomicAdd(&s_cnt, cntds);
    atomicMin(&s_minx, minx);
    atomicMax(&s_maxx, maxx);
    atomicMin(&s_miny, miny);
    atomicMax(&s_maxy, maxy);
  }
  __syncthreads();

  float* ws_ds = ws + DS_OFF + (size_t)bk * 576;
  if (t < 576) ws_ds[t] = ds[t];

  if (t == 0) {
    float* meta = ws + META_OFF + (size_t)bk * 8;
    float areaf = (float)s_area;
    float safe  = fmaxf(areaf, 1.0f);
    float cx = ((float)s_sumx / safe) * (1.0f / Ww);
    float cy = ((float)s_sumy / safe) * (1.0f / Hh);
    float an = areaf * (1.0f / (Hh * Ww));
    float bw = (float)(s_maxx - s_minx + 1) * (1.0f / Ww);
    float bh = (float)(s_maxy - s_miny + 1) * (1.0f / Hh);
    if (s_area < 1) { cx = 0.f; cy = 0.f; an = 0.f; bw = 0.f; bh = 0.f; }
    meta[0] = cx; meta[1] = cy; meta[2] = an; meta[3] = bw; meta[4] = bh;
    meta[5] = 1.0f / fmaxf((float)s_cnt, 1e-6f);
    meta[6] = (float)s_cnt;
  }
}

// ---------------- Kernel BC: pooling + MLP fused, one block per (b,k) ----------------
// b = blockIdx%8 so all 32 k-blocks of one b share an XCD L2 (fm slice 2.36MB < 4MB).
// x row lives in LDS; GEMV1 K-split across the 4 waves (each wave broadcasts
// its own 292-element x chunk => 4x fewer LDS broadcast issues).
__global__ __launch_bounds__(256) void kBC(const float* __restrict__ fm,
                                           const int* __restrict__ cids,
                                           const float* __restrict__ emb,
                                           const float* __restrict__ W1,
                                           const float* __restrict__ b1,
                                           const float* __restrict__ lg,
                                           const float* __restrict__ lb,
                                           const float* __restrict__ W2,
                                           const float* __restrict__ b2,
                                           const float* __restrict__ ws,
                                           float* __restrict__ out) {
  const int b    = blockIdx.x & 7;
  const int k    = blockIdx.x >> 3;
  const int bk   = b * Kk + k;
  const int t    = threadIdx.x;
  const int lane = t & 63;
  const int w    = t >> 6;

  __shared__ float4 x4s[292];        // 1168 floats; [0,1093) data, rest zero
  __shared__ int   act[576];
  __shared__ int   nact;
  __shared__ float partial[4 * 256];
  __shared__ float hrow[256];
  __shared__ float red[8];
  float* x = (float*)x4s;

  if (t == 0) nact = 0;
  __syncthreads();

  const float* dsrow = ws + DS_OFF + (size_t)bk * 576;
  for (int i = t; i < 576; i += 256) {
    float mv = dsrow[i];
    if (mv != 0.0f) act[atomicAdd(&nact, 1)] = i;
  }
  if (t < 75) x[1093 + t] = 0.0f;    // zero pad tail of x (1093..1167)
  __syncthreads();
  const int na = nact;

  // ---- pooling: thread t owns float4 chunk t of D ----
  const float* meta = ws + META_OFF + (size_t)bk * 8;
  float inv = meta[5];
  float ax = 0.f, ay = 0.f, az = 0.f, aw = 0.f;
  const float4* fmp = (const float4*)fm + (size_t)b * Nn * (Dd / 4);
  int j = 0;
  for (; j + 4 <= na; j += 4) {
    int4 nn = *(const int4*)(act + j);
    float4 f0 = fmp[nn.x * (Dd / 4) + t];
    float4 f1 = fmp[nn.y * (Dd / 4) + t];
    float4 f2 = fmp[nn.z * (Dd / 4) + t];
    float4 f3 = fmp[nn.w * (Dd / 4) + t];
    ax += f0.x + f1.x + f2.x + f3.x;
    ay += f0.y + f1.y + f2.y + f3.y;
    az += f0.z + f1.z + f2.z + f3.z;
    aw += f0.w + f1.w + f2.w + f3.w;
  }
  for (; j < na; j++) {
    float4 f = fmp[act[j] * (Dd / 4) + t];
    ax += f.x; ay += f.y; az += f.z; aw += f.w;
  }
  float4 p;
  p.x = ax * inv; p.y = ay * inv; p.z = az * inv; p.w = aw * inv;
  x4s[t] = p;                                   // x[0..1024)
  if (t < CLSD) x[Dd + t] = emb[(size_t)cids[bk] * CLSD + t];  // cls emb
  else if (t < CLSD + 5) x[Dd + t] = meta[t - CLSD];           // geom
  __syncthreads();

  // ---- GEMV1: wave w handles K-chunk [w*292, min(1093, w*292+292)) ----
  const int kbeg = w * 292;
  const int kend = min(INDIM, kbeg + 292);
  float acc0 = 0.f, acc1 = 0.f, acc2 = 0.f, acc3 = 0.f;
  int kk = kbeg;
  for (; kk + 4 <= kend; kk += 4) {
    float4 xv = x4s[kk >> 2];                   // wave-uniform LDS broadcast
    const float* xs = (const float*)&xv;
#pragma unroll
    for (int u = 0; u < 4; u++) {
      float xval = xs[u];
      const float* wrow = W1 + (size_t)(kk + u) * OUTD;
      acc0 = fmaf(xval, wrow[lane], acc0);
      acc1 = fmaf(xval, wrow[lane + 64], acc1);
      acc2 = fmaf(xval, wrow[lane + 128], acc2);
      acc3 = fmaf(xval, wrow[lane + 192], acc3);
    }
  }
  for (; kk < kend; kk++) {                     // scalar tail (wave 3 only)
    float xval = x[kk];
    const float* wrow = W1 + (size_t)kk * OUTD;
    acc0 = fmaf(xval, wrow[lane], acc0);
    acc1 = fmaf(xval, wrow[lane + 64], acc1);
    acc2 = fmaf(xval, wrow[lane + 128], acc2);
    acc3 = fmaf(xval, wrow[lane + 192], acc3);
  }
  partial[w * 256 + lane] = acc0;
  partial[w * 256 + lane + 64] = acc1;
  partial[w * 256 + lane + 128] = acc2;
  partial[w * 256 + lane + 192] = acc3;
  __syncthreads();

  // ---- combine + GeLU + LayerNorm ----
  float hval = partial[t] + partial[256 + t] + partial[512 + t] + partial[768 + t] + b1[t];
  hval = 0.5f * hval * (1.0f + erff(hval * 0.7071067811865475f));
  float s = hval, q = hval * hval;
  for (int off = 32; off; off >>= 1) {
    s += __shfl_down(s, off);
    q += __shfl_down(q, off);
  }
  if (lane == 0) { red[w] = s; red[4 + w] = q; }
  __syncthreads();
  float mu  = (red[0] + red[1] + red[2] + red[3]) * (1.0f / OUTD);
  float var = (red[4] + red[5] + red[6] + red[7]) * (1.0f / OUTD) - mu * mu;
  float ist = 1.0f / sqrtf(var + 1e-5f);
  float hn  = (hval - mu) * ist * lg[t] + lb[t];
  hrow[t] = hn;
  __syncthreads();

  // ---- GEMV2: thread t owns output t ----
  float c = b2[t];
  const float4* h4 = (const float4*)hrow;
  for (int i = 0; i < 64; i++) {
    float4 hv = h4[i];                          // wave-uniform LDS broadcast
    const float* hs = (const float*)&hv;
#pragma unroll
    for (int u = 0; u < 4; u++)
      c = fmaf(hs[u], W2[(size_t)(i * 4 + u) * OUTD + t], c);
  }
  out[(size_t)bk * OUTD + t] = c;
}

extern "C" void kernel_launch(void* const* d_in, const int* in_sizes, int n_in,
                              void* d_out, int out_size, void* d_ws, size_t ws_size,
                              hipStream_t stream) {
  const float* fm    = (const float*)d_in[0];
  const int*   masks = (const int*)d_in[1];
  const int*   cids  = (const int*)d_in[2];
  const float* emb   = (const float*)d_in[3];
  const float* W1    = (const float*)d_in[4];
  const float* b1    = (const float*)d_in[5];
  const float* lg    = (const float*)d_in[6];
  const float* lb    = (const float*)d_in[7];
  const float* W2    = (const float*)d_in[8];
  const float* b2    = (const float*)d_in[9];
  float* out = (float*)d_out;
  float* ws  = (float*)d_ws;

  hipLaunchKernelGGL(kA, dim3(BK), dim3(1024), 0, stream, masks, ws);
  hipLaunchKernelGGL(kBC, dim3(BK), dim3(256), 0, stream, fm, cids, emb,
                     W1, b1, lg, lb, W2, b2, ws, out);
}

// Round 3
// 374.534 us; speedup vs baseline: 1.1397x; 1.1090x over previous
//
#include <hip/hip_runtime.h>
#include <math.h>

// Problem constants
#define Bb 8
#define Kk 32
#define Hh 480
#define Ww 480
#define Nn 576
#define Dd 1024
#define CLSD 64
#define OUTD 256
#define INDIM 1093
#define BK 256           // B*K
#define PIX4 57600       // 480*480/4 int4 per (b,k)

// Fully fused: one 1024-thread block per (b,k).
//   Phase 1: full-res mask scan (236 MB total -> HBM floor ~37us)
//   Phase 2: geom/meta + active-index list (LDS only)
//   Phase 3: masked pooling, 4-way N-split across thread groups, float4 fm loads
//   Phase 4: GEMV1 1093x256, 16-way wave K-split, float4 W1 loads (1KB/wave/K)
//   Phase 5: GeLU + LayerNorm
//   Phase 6: GEMV2 256x256, 16-way wave K-split, float4 W2 loads
// b = blockIdx%8 so the 32 k-blocks of one b share an XCD L2 (fm slice 2.36MB).
__global__ __launch_bounds__(1024) void kF(const int* __restrict__ masks,
                                           const float* __restrict__ fm,
                                           const int* __restrict__ cids,
                                           const float* __restrict__ emb,
                                           const float* __restrict__ W1,
                                           const float* __restrict__ b1,
                                           const float* __restrict__ lg,
                                           const float* __restrict__ lb,
                                           const float* __restrict__ W2,
                                           const float* __restrict__ b2,
                                           float* __restrict__ out) {
  const int b    = blockIdx.x & 7;
  const int k    = blockIdx.x >> 3;
  const int bk   = b * Kk + k;
  const int t    = threadIdx.x;
  const int lane = t & 63;
  const int w    = t >> 6;          // wave id 0..15

  __shared__ float  ds[576];
  __shared__ int    act[576];
  __shared__ float4 x4s[292];       // x row: 1168 floats, [0,1093) data, rest 0
  __shared__ float4 pp[4 * 256];    // pooling partials (16 KB)
  __shared__ float  partial[16 * 256]; // GEMV partials (16 KB)
  __shared__ float  hrow[256];
  __shared__ float  red_s[16], red_q[16];
  __shared__ float  gmeta[8];
  __shared__ int s_area, s_sumx, s_sumy, s_cnt;
  __shared__ int s_minx, s_maxx, s_miny, s_maxy, nact;
  float* x = (float*)x4s;

  if (t == 0) {
    s_area = 0; s_sumx = 0; s_sumy = 0; s_cnt = 0;
    s_minx = Ww; s_maxx = -1; s_miny = Hh; s_maxy = -1;
    nact = 0;
  }
  __syncthreads();

  // ---------------- Phase 1: mask scan ----------------
  const int4* mp = (const int4*)(masks + (size_t)bk * (Hh * Ww));
  int area = 0, sumx = 0, sumy = 0, cntds = 0;
  int minx = Ww, maxx = -1, miny = Hh, maxy = -1;

  auto body = [&](int q, int4 v) {
    int h   = q / 120;              // 120 int4 per row (magic-mul)
    int rem = q - h * 120;
    int w0  = rem * 4;
    int m0 = v.x > 0, m1 = v.y > 0, m2 = v.z > 0, m3 = v.w > 0;
    int c = m0 + m1 + m2 + m3;
    area += c;
    sumy += h * c;
    sumx += w0 * c + m1 + 2 * m2 + 3 * m3;
    if (c) {
      miny = min(miny, h);
      maxy = max(maxy, h);
      int lo = m0 ? w0 : (m1 ? w0 + 1 : (m2 ? w0 + 2 : w0 + 3));
      int hi = m3 ? w0 + 3 : (m2 ? w0 + 2 : (m1 ? w0 + 1 : w0));
      minx = min(minx, lo);
      maxx = max(maxx, hi);
    }
    // nearest-neighbor sample points: h%20==0 && (w0%20==0 <=> rem%5==0)
    int a20 = h / 20;
    int c5  = rem / 5;
    if (h == a20 * 20 && rem == c5 * 5) {
      ds[a20 * 24 + c5] = (float)m0;
      cntds += m0;
    }
  };

#pragma unroll 4
  for (int i = 0; i < 56; i++) {
    int q = t + (i << 10);
    body(q, mp[q]);
  }
  if (t < 256) {
    int q = 57344 + t;
    body(q, mp[q]);
  }

  for (int off = 32; off; off >>= 1) {
    area  += __shfl_down(area, off);
    sumx  += __shfl_down(sumx, off);
    sumy  += __shfl_down(sumy, off);
    cntds += __shfl_down(cntds, off);
    minx = min(minx, __shfl_down(minx, off));
    maxx = max(maxx, __shfl_down(maxx, off));
    miny = min(miny, __shfl_down(miny, off));
    maxy = max(maxy, __shfl_down(maxy, off));
  }
  if (lane == 0) {
    atomicAdd(&s_area, area);
    atomicAdd(&s_sumx, sumx);
    atomicAdd(&s_sumy, sumy);
    atomicAdd(&s_cnt, cntds);
    atomicMin(&s_minx, minx);
    atomicMax(&s_maxx, maxx);
    atomicMin(&s_miny, miny);
    atomicMax(&s_maxy, maxy);
  }
  __syncthreads();

  // ---------------- Phase 2: meta + active list ----------------
  if (t == 0) {
    float areaf = (float)s_area;
    float safe  = fmaxf(areaf, 1.0f);
    float cx = ((float)s_sumx / safe) * (1.0f / Ww);
    float cy = ((float)s_sumy / safe) * (1.0f / Hh);
    float an = areaf * (1.0f / (Hh * Ww));
    float bw = (float)(s_maxx - s_minx + 1) * (1.0f / Ww);
    float bh = (float)(s_maxy - s_miny + 1) * (1.0f / Hh);
    if (s_area < 1) { cx = 0.f; cy = 0.f; an = 0.f; bw = 0.f; bh = 0.f; }
    gmeta[0] = cx; gmeta[1] = cy; gmeta[2] = an; gmeta[3] = bw; gmeta[4] = bh;
    gmeta[5] = 1.0f / fmaxf((float)s_cnt, 1e-6f);
  }
  if (t < 576 && ds[t] != 0.0f) act[atomicAdd(&nact, 1)] = t;
  if (t < 75) x[1093 + t] = 0.0f;   // zero pad x[1093..1167]
  __syncthreads();
  const int na = nact;

  // ---------------- Phase 3: pooling (4-way N-split) ----------------
  {
    const int g   = t >> 8;         // group 0..3 (4 waves each)
    const int col = t & 255;
    const int jb  = (na * g) >> 2;
    const int je  = (na * (g + 1)) >> 2;
    const float4* fmp = (const float4*)fm + (size_t)b * Nn * (Dd / 4);
    float ax = 0.f, ay = 0.f, az = 0.f, aw = 0.f;
    int j = jb;
    for (; j + 4 <= je; j += 4) {
      int n0 = act[j], n1 = act[j + 1], n2 = act[j + 2], n3 = act[j + 3];
      float4 f0 = fmp[n0 * (Dd / 4) + col];
      float4 f1 = fmp[n1 * (Dd / 4) + col];
      float4 f2 = fmp[n2 * (Dd / 4) + col];
      float4 f3 = fmp[n3 * (Dd / 4) + col];
      ax += f0.x + f1.x + f2.x + f3.x;
      ay += f0.y + f1.y + f2.y + f3.y;
      az += f0.z + f1.z + f2.z + f3.z;
      aw += f0.w + f1.w + f2.w + f3.w;
    }
    for (; j < je; j++) {
      float4 f = fmp[act[j] * (Dd / 4) + col];
      ax += f.x; ay += f.y; az += f.z; aw += f.w;
    }
    float4 p; p.x = ax; p.y = ay; p.z = az; p.w = aw;
    pp[g * 256 + col] = p;
  }
  __syncthreads();

  if (t < 256) {
    float inv = gmeta[5];
    float4 a0 = pp[t], a1 = pp[256 + t], a2 = pp[512 + t], a3 = pp[768 + t];
    float4 p;
    p.x = (a0.x + a1.x + a2.x + a3.x) * inv;
    p.y = (a0.y + a1.y + a2.y + a3.y) * inv;
    p.z = (a0.z + a1.z + a2.z + a3.z) * inv;
    p.w = (a0.w + a1.w + a2.w + a3.w) * inv;
    x4s[t] = p;
  } else if (t < 320) {
    x[Dd + (t - 256)] = emb[(size_t)cids[bk] * CLSD + (t - 256)];
  } else if (t < 325) {
    x[Dd + CLSD + (t - 320)] = gmeta[t - 320];
  }
  __syncthreads();

  // ---------------- Phase 4: GEMV1, 16-way wave K-split, float4 W1 loads ----
  // lane l owns outputs [4l, 4l+4); wave w owns K-chunk [72w, min(1093,72w+72))
  {
    const int kbeg = w * 72;
    const int kend = min(INDIM, kbeg + 72);
    float4 acc = {0.f, 0.f, 0.f, 0.f};
    int kk = kbeg;
    for (; kk + 4 <= kend; kk += 4) {
      float4 xv = x4s[kk >> 2];     // wave-uniform LDS broadcast
      const float* xs = (const float*)&xv;
#pragma unroll
      for (int u = 0; u < 4; u++) {
        float4 w4 = *(const float4*)(W1 + (size_t)(kk + u) * OUTD + 4 * lane);
        acc.x = fmaf(xs[u], w4.x, acc.x);
        acc.y = fmaf(xs[u], w4.y, acc.y);
        acc.z = fmaf(xs[u], w4.z, acc.z);
        acc.w = fmaf(xs[u], w4.w, acc.w);
      }
    }
    for (; kk < kend; kk++) {       // tail (wave 15 only: k=1092)
      float xv = x[kk];
      float4 w4 = *(const float4*)(W1 + (size_t)kk * OUTD + 4 * lane);
      acc.x = fmaf(xv, w4.x, acc.x);
      acc.y = fmaf(xv, w4.y, acc.y);
      acc.z = fmaf(xv, w4.z, acc.z);
      acc.w = fmaf(xv, w4.w, acc.w);
    }
    *(float4*)(partial + w * 256 + 4 * lane) = acc;
  }
  __syncthreads();

  // ---------------- Phase 5: combine + GeLU + LayerNorm ----------------
  float hv = 0.f;
  if (t < 256) {
    hv = b1[t];
#pragma unroll
    for (int ww = 0; ww < 16; ww++) hv += partial[ww * 256 + t];
    hv = 0.5f * hv * (1.0f + erff(hv * 0.7071067811865475f));
  }
  {
    float s = hv, q = hv * hv;
    for (int off = 32; off; off >>= 1) {
      s += __shfl_down(s, off);
      q += __shfl_down(q, off);
    }
    if (lane == 0) { red_s[w] = s; red_q[w] = q; }
  }
  __syncthreads();
  if (t < 256) {
    float s = 0.f, q = 0.f;
#pragma unroll
    for (int ww = 0; ww < 16; ww++) { s += red_s[ww]; q += red_q[ww]; }
    float mu  = s * (1.0f / OUTD);
    float var = q * (1.0f / OUTD) - mu * mu;
    float ist = 1.0f / sqrtf(var + 1e-5f);
    hrow[t] = (hv - mu) * ist * lg[t] + lb[t];
  }
  __syncthreads();

  // ---------------- Phase 6: GEMV2, 16-way wave K-split, float4 W2 loads ----
  {
    float4 acc = {0.f, 0.f, 0.f, 0.f};
#pragma unroll
    for (int i = 0; i < 4; i++) {
      float4 h4 = ((const float4*)hrow)[w * 4 + i];
      const float* hs = (const float*)&h4;
#pragma unroll
      for (int u = 0; u < 4; u++) {
        int kk = w * 16 + i * 4 + u;
        float4 w4 = *(const float4*)(W2 + (size_t)kk * OUTD + 4 * lane);
        acc.x = fmaf(hs[u], w4.x, acc.x);
        acc.y = fmaf(hs[u], w4.y, acc.y);
        acc.z = fmaf(hs[u], w4.z, acc.z);
        acc.w = fmaf(hs[u], w4.w, acc.w);
      }
    }
    *(float4*)(partial + w * 256 + 4 * lane) = acc;
  }
  __syncthreads();

  if (t < 256) {
    float c = b2[t];
#pragma unroll
    for (int ww = 0; ww < 16; ww++) c += partial[ww * 256 + t];
    out[(size_t)bk * OUTD + t] = c;
  }
}

extern "C" void kernel_launch(void* const* d_in, const int* in_sizes, int n_in,
                              void* d_out, int out_size, void* d_ws, size_t ws_size,
                              hipStream_t stream) {
  const float* fm    = (const float*)d_in[0];
  const int*   masks = (const int*)d_in[1];
  const int*   cids  = (const int*)d_in[2];
  const float* emb   = (const float*)d_in[3];
  const float* W1    = (const float*)d_in[4];
  const float* b1    = (const float*)d_in[5];
  const float* lg    = (const float*)d_in[6];
  const float* lb    = (const float*)d_in[7];
  const float* W2    = (const float*)d_in[8];
  const float* b2    = (const float*)d_in[9];
  float* out = (float*)d_out;

  hipLaunchKernelGGL(kF, dim3(BK), dim3(1024), 0, stream, masks, fm, cids, emb,
                     W1, b1, lg, lb, W2, b2, out);
}

// Round 4
// 372.943 us; speedup vs baseline: 1.1446x; 1.0043x over previous
//
#include <hip/hip_runtime.h>
#include <math.h>

// Problem constants
#define Bb 8
#define Kk 32
#define Hh 480
#define Ww 480
#define Nn 576
#define Dd 1024
#define CLSD 64
#define OUTD 256
#define INDIM 1093
#define BK 256           // B*K
#define PIX4 57600       // 480*480/4 int4 per (b,k)

// Fully fused, overlap-structured: one 1024-thread block per (b,k).
//   Phase 0: sample the 576 downsample pixels directly -> act list (cnt=nact)
//   Parallel section:
//     waves 0-11 : full-res mask scan for geom stats (HBM-bound, ~37us chip-wide)
//     waves 12-15: pooling (L2-served fm) + GEMV1 K in [0,1024) (L2-served W1)
//                  -- each consumer wave pools its own 256-col slice and GEMV1s
//                     exactly that K-slice => no cross-wave dependency.
//   Epilogue: geom finalize, cls-emb + geom GEMV1 tail, GeLU, LN, GEMV2, store.
// b = blockIdx%8: the 32 k-blocks of one b share an XCD L2 (fm slice 2.36MB).
__global__ __launch_bounds__(1024) void kF(const int* __restrict__ masks,
                                           const float* __restrict__ fm,
                                           const int* __restrict__ cids,
                                           const float* __restrict__ emb,
                                           const float* __restrict__ W1,
                                           const float* __restrict__ b1,
                                           const float* __restrict__ lg,
                                           const float* __restrict__ lb,
                                           const float* __restrict__ W2,
                                           const float* __restrict__ b2,
                                           float* __restrict__ out) {
  const int b    = blockIdx.x & 7;
  const int k    = blockIdx.x >> 3;
  const int bk   = b * Kk + k;
  const int t    = threadIdx.x;
  const int lane = t & 63;
  const int w    = t >> 6;          // wave id 0..15

  __shared__ int    act[576];
  __shared__ float4 x4s[256];       // per-consumer-wave x staging (4 KB)
  __shared__ float  partial[16 * 256]; // GEMV partials (16 KB)
  __shared__ float  hrow[256];
  __shared__ float  red_s[4], red_q[4];
  __shared__ float  gmeta[8];
  __shared__ int s_area, s_sumx, s_sumy;
  __shared__ int s_minx, s_maxx, s_miny, s_maxy, nact;

  if (t == 0) {
    s_area = 0; s_sumx = 0; s_sumy = 0;
    s_minx = Ww; s_maxx = -1; s_miny = Hh; s_maxy = -1;
    nact = 0;
  }
  __syncthreads();

  // ---------------- Phase 0: direct downsample sampling ----------------
  // ds pixel i=(a,c): mask[(20a)*480 + 20c]; cnt == nact
  const int* mbase = masks + (size_t)bk * (Hh * Ww);
  if (t < 576) {
    int a = t / 24, c = t - a * 24;
    if (mbase[a * 20 * Ww + c * 20] > 0) act[atomicAdd(&nact, 1)] = t;
  }
  __syncthreads();
  const int na = nact;

  if (w < 12) {
    // ============ SCAN (768 threads, 75 clean iterations) ============
    int area = 0, sumx = 0, sumy = 0;
    int minx = Ww, maxx = -1, miny = Hh, maxy = -1;
    const int4* mp = (const int4*)mbase;
#pragma unroll 5
    for (int i = 0; i < 75; i++) {
      int q = t + i * 768;
      int4 v = mp[q];
      int h   = q / 120;            // 120 int4 per row (magic-mul)
      int rem = q - h * 120;
      int w0  = rem * 4;
      int m0 = v.x > 0, m1 = v.y > 0, m2 = v.z > 0, m3 = v.w > 0;
      int c = m0 + m1 + m2 + m3;
      area += c;
      sumy += h * c;
      sumx += w0 * c + m1 + 2 * m2 + 3 * m3;
      if (c) {
        miny = min(miny, h);
        maxy = max(maxy, h);
        int lo = m0 ? w0 : (m1 ? w0 + 1 : (m2 ? w0 + 2 : w0 + 3));
        int hi = m3 ? w0 + 3 : (m2 ? w0 + 2 : (m1 ? w0 + 1 : w0));
        minx = min(minx, lo);
        maxx = max(maxx, hi);
      }
    }
    for (int off = 32; off; off >>= 1) {
      area += __shfl_down(area, off);
      sumx += __shfl_down(sumx, off);
      sumy += __shfl_down(sumy, off);
      minx = min(minx, __shfl_down(minx, off));
      maxx = max(maxx, __shfl_down(maxx, off));
      miny = min(miny, __shfl_down(miny, off));
      maxy = max(maxy, __shfl_down(maxy, off));
    }
    if (lane == 0) {
      atomicAdd(&s_area, area);
      atomicAdd(&s_sumx, sumx);
      atomicAdd(&s_sumy, sumy);
      atomicMin(&s_minx, minx);
      atomicMax(&s_maxx, maxx);
      atomicMin(&s_miny, miny);
      atomicMax(&s_maxy, maxy);
    }
  } else {
    // ============ CONSUMER (4 waves): pooling + GEMV1 K<1024 ============
    const int cw   = w - 12;        // 0..3
    const int base = cw * 64 + lane;  // float4 col index owned by this lane
    const float4* fmp = (const float4*)fm + (size_t)b * Nn * (Dd / 4);
    float ax = 0.f, ay = 0.f, az = 0.f, aw = 0.f;
    int j = 0;
    for (; j + 4 <= na; j += 4) {
      int n0 = act[j], n1 = act[j + 1], n2 = act[j + 2], n3 = act[j + 3];
      float4 f0 = fmp[n0 * (Dd / 4) + base];
      float4 f1 = fmp[n1 * (Dd / 4) + base];
      float4 f2 = fmp[n2 * (Dd / 4) + base];
      float4 f3 = fmp[n3 * (Dd / 4) + base];
      ax += f0.x + f1.x + f2.x + f3.x;
      ay += f0.y + f1.y + f2.y + f3.y;
      az += f0.z + f1.z + f2.z + f3.z;
      aw += f0.w + f1.w + f2.w + f3.w;
    }
    for (; j < na; j++) {
      float4 f = fmp[act[j] * (Dd / 4) + base];
      ax += f.x; ay += f.y; az += f.z; aw += f.w;
    }
    float inv = 1.0f / fmaxf((float)na, 1e-6f);
    float4 xp;
    xp.x = ax * inv; xp.y = ay * inv; xp.z = az * inv; xp.w = aw * inv;
    x4s[base] = xp;                 // same-wave LDS stage (no barrier needed)

    // GEMV1 over this wave's own K-slice [256cw, 256cw+256)
    float4 acc = {0.f, 0.f, 0.f, 0.f};
    const float* W1b = W1 + (size_t)(cw * 256) * OUTD + 4 * lane;
#pragma unroll 2
    for (int g = 0; g < 64; g++) {
      float4 xv = x4s[cw * 64 + g]; // wave-uniform LDS broadcast
      const float* xs = (const float*)&xv;
#pragma unroll
      for (int u = 0; u < 4; u++) {
        float4 w4 = *(const float4*)(W1b + (size_t)(4 * g + u) * OUTD);
        acc.x = fmaf(xs[u], w4.x, acc.x);
        acc.y = fmaf(xs[u], w4.y, acc.y);
        acc.z = fmaf(xs[u], w4.z, acc.z);
        acc.w = fmaf(xs[u], w4.w, acc.w);
      }
    }
    *(float4*)(partial + cw * 256 + 4 * lane) = acc;
  }
  __syncthreads();

  // ---------------- Epilogue ----------------
  if (t == 0) {
    float areaf = (float)s_area;
    float safe  = fmaxf(areaf, 1.0f);
    float cx = ((float)s_sumx / safe) * (1.0f / Ww);
    float cy = ((float)s_sumy / safe) * (1.0f / Hh);
    float an = areaf * (1.0f / (Hh * Ww));
    float bw = (float)(s_maxx - s_minx + 1) * (1.0f / Ww);
    float bh = (float)(s_maxy - s_miny + 1) * (1.0f / Hh);
    if (s_area < 1) { cx = 0.f; cy = 0.f; an = 0.f; bw = 0.f; bh = 0.f; }
    gmeta[0] = cx; gmeta[1] = cy; gmeta[2] = an; gmeta[3] = bw; gmeta[4] = bh;
  }
  __syncthreads();

  // combine + cls/geom GEMV1 tail + GeLU  (threads 0..255)
  float hv = 0.f;
  if (t < 256) {
    hv = b1[t] + partial[t] + partial[256 + t] + partial[512 + t] + partial[768 + t];
    const float* et = emb + (size_t)cids[bk] * CLSD;
#pragma unroll 8
    for (int i = 0; i < CLSD; i++)
      hv = fmaf(et[i], W1[(size_t)(Dd + i) * OUTD + t], hv);
#pragma unroll
    for (int jj = 0; jj < 5; jj++)
      hv = fmaf(gmeta[jj], W1[(size_t)(Dd + CLSD + jj) * OUTD + t], hv);
    hv = 0.5f * hv * (1.0f + erff(hv * 0.7071067811865475f));
  }
  {
    float s = hv, q = hv * hv;
    for (int off = 32; off; off >>= 1) {
      s += __shfl_down(s, off);
      q += __shfl_down(q, off);
    }
    if (lane == 0 && w < 4) { red_s[w] = s; red_q[w] = q; }
  }
  __syncthreads();
  if (t < 256) {
    float s = red_s[0] + red_s[1] + red_s[2] + red_s[3];
    float q = red_q[0] + red_q[1] + red_q[2] + red_q[3];
    float mu  = s * (1.0f / OUTD);
    float var = q * (1.0f / OUTD) - mu * mu;
    float ist = 1.0f / sqrtf(var + 1e-5f);
    hrow[t] = (hv - mu) * ist * lg[t] + lb[t];
  }
  __syncthreads();

  // GEMV2: 16-way wave K-split, float4 W2 loads
  {
    float4 acc = {0.f, 0.f, 0.f, 0.f};
#pragma unroll
    for (int i = 0; i < 4; i++) {
      float4 h4 = ((const float4*)hrow)[w * 4 + i];
      const float* hs = (const float*)&h4;
#pragma unroll
      for (int u = 0; u < 4; u++) {
        int kk = w * 16 + i * 4 + u;
        float4 w4 = *(const float4*)(W2 + (size_t)kk * OUTD + 4 * lane);
        acc.x = fmaf(hs[u], w4.x, acc.x);
        acc.y = fmaf(hs[u], w4.y, acc.y);
        acc.z = fmaf(hs[u], w4.z, acc.z);
        acc.w = fmaf(hs[u], w4.w, acc.w);
      }
    }
    *(float4*)(partial + w * 256 + 4 * lane) = acc;
  }
  __syncthreads();

  if (t < 256) {
    float c = b2[t];
#pragma unroll
    for (int ww = 0; ww < 16; ww++) c += partial[ww * 256 + t];
    out[(size_t)bk * OUTD + t] = c;
  }
}

extern "C" void kernel_launch(void* const* d_in, const int* in_sizes, int n_in,
                              void* d_out, int out_size, void* d_ws, size_t ws_size,
                              hipStream_t stream) {
  const float* fm    = (const float*)d_in[0];
  const int*   masks = (const int*)d_in[1];
  const int*   cids  = (const int*)d_in[2];
  const float* emb   = (const float*)d_in[3];
  const float* W1    = (const float*)d_in[4];
  const float* b1    = (const float*)d_in[5];
  const float* lg    = (const float*)d_in[6];
  const float* lb    = (const float*)d_in[7];
  const float* W2    = (const float*)d_in[8];
  const float* b2    = (const float*)d_in[9];
  float* out = (float*)d_out;

  hipLaunchKernelGGL(kF, dim3(BK), dim3(1024), 0, stream, masks, fm, cids, emb,
                     W1, b1, lg, lb, W2, b2, out);
}